// Round 1
// baseline (941.118 us; speedup 1.0000x reference)
//
#include <hip/hip_runtime.h>
#include <hip/hip_bf16.h>
#include <math.h>

#define Bb 4
#define Nn 2048
#define DIMd 128
#define Kk 32
#define H1 530      // EDGE_IN*2
#define PW 1060     // P table width (i-part | j-part)
#define MD 16
#define NDH 256
#define NDI 144

typedef float f32x4 __attribute__((ext_vector_type(4)));
typedef short s16x8 __attribute__((ext_vector_type(8)));

__device__ __forceinline__ unsigned short f2bf(float f){
    union { float f; unsigned u; } v; v.f = f;
    unsigned r = v.u + 0x7FFFu + ((v.u >> 16) & 1u);
    return (unsigned short)(r >> 16);
}
__device__ __forceinline__ float silu_f(float x){ return x / (1.0f + __expf(-x)); }

// ---------------- Kernel A: exact top-K=32 nearest (squared dist, low-index tiebreak) ----------
__global__ __launch_bounds__(256) void topk_kernel(const float* __restrict__ coors,
        int* __restrict__ idx_ws, float* __restrict__ dv_ws){
    __shared__ float dist[Nn];
    __shared__ float rd[4]; __shared__ int rj[4]; __shared__ int sel;
    int node = blockIdx.x; int b = node >> 11;
    int tid = threadIdx.x;
    const float* cbp = coors + (size_t)b * Nn * 3;
    float cx = coors[node*3+0], cy = coors[node*3+1], cz = coors[node*3+2];
    for (int j = tid; j < Nn; j += 256){
        float dx = cx - cbp[j*3+0], dy = cy - cbp[j*3+1], dz = cz - cbp[j*3+2];
        dist[j] = dx*dx + dy*dy + dz*dz;
    }
    __syncthreads();
    float md = 3.4e38f; int mj = 0x7fffffff;
    #pragma unroll
    for (int t=0;t<8;t++){ int j = tid + t*256; float d = dist[j]; if (d < md){ md=d; mj=j; } }
    for (int r = 0; r < Kk; r++){
        float d = md; int j = mj;
        #pragma unroll
        for (int off=32; off; off>>=1){
            float d2 = __shfl_xor(d, off); int j2 = __shfl_xor(j, off);
            if (d2 < d || (d2 == d && j2 < j)){ d = d2; j = j2; }
        }
        if ((tid & 63) == 0){ rd[tid>>6] = d; rj[tid>>6] = j; }
        __syncthreads();
        if (tid == 0){
            float bd = rd[0]; int bj = rj[0];
            for (int w=1; w<4; w++) if (rd[w] < bd || (rd[w]==bd && rj[w]<bj)){ bd=rd[w]; bj=rj[w]; }
            idx_ws[node*Kk + r] = bj;
            dv_ws[node*Kk + r] = bd;
            dist[bj] = 3.4e38f;
            sel = bj;
        }
        __syncthreads();
        if ((sel & 255) == tid){   // owner of the removed element rescans its 8 slots
            md = 3.4e38f; mj = 0x7fffffff;
            #pragma unroll
            for (int t=0;t<8;t++){ int j2 = tid + t*256; float dd = dist[j2]; if (dd < md){ md=dd; mj=j2; } }
        }
    }
}

// ---------------- Kernel B: P[node][0:530]=feats@eW1_i+eb1 ; P[node][530:1060]=feats@eW1_j ----
__global__ __launch_bounds__(256) void pmat_kernel(const float* __restrict__ feats,
        const float* __restrict__ eW1, const float* __restrict__ eb1,
        float* __restrict__ P){
    __shared__ float fs[16][128];
    int tid = threadIdx.x;
    int node0 = blockIdx.x * 16;
    for (int t = tid; t < 16*128; t += 256) fs[t>>7][t&127] = feats[(size_t)node0*DIMd + t];
    __syncthreads();
    int c = blockIdx.y * 256 + tid;
    if (c >= PW) return;
    int col, rbase; float bias;
    if (c < H1){ col = c; rbase = 0; bias = eb1[c]; }
    else { col = c - H1; rbase = 128; bias = 0.f; }
    float acc[16];
    #pragma unroll
    for (int m=0;m<16;m++) acc[m] = bias;
    for (int k=0;k<128;k++){
        float w = eW1[(rbase+k)*H1 + col];
        #pragma unroll
        for (int m=0;m<16;m++) acc[m] += fs[m][k]*w;
    }
    #pragma unroll
    for (int m=0;m<16;m++) P[(size_t)(node0+m)*PW + c] = acc[m];
}

// ---------------- Kernel C: per-node edge pipeline -------------------------------------------
__global__ __launch_bounds__(256) void edge_kernel(const float* __restrict__ coors,
        const float* __restrict__ eW1, const float* __restrict__ eW2, const float* __restrict__ eb2,
        const float* __restrict__ cW1, const float* __restrict__ cb1,
        const float* __restrict__ cW2, const float* __restrict__ cb2,
        const float* __restrict__ P, const int* __restrict__ idx_ws, const float* __restrict__ dv_ws,
        float* __restrict__ mi_ws, float* __restrict__ coors_out){
    __shared__ float Pi[H1];
    __shared__ float W1e[9][H1];
    __shared__ float encs[Kk][9];
    __shared__ float rels[Kk][3];
    __shared__ int js[Kk];
    __shared__ unsigned short Hs[Kk][544];   // bf16, K padded 530->544
    __shared__ unsigned short W2T[16][544];  // eW2 transposed, bf16, padded
    __shared__ float m_s[Kk][MD];
    __shared__ float cacc[4][3];
    int node = blockIdx.x; int tid = threadIdx.x;
    int b = node >> 11;
    int wid = tid >> 6, lane = tid & 63;

    for (int c = tid; c < H1; c += 256) Pi[c] = P[(size_t)node*PW + c];
    #pragma unroll
    for (int e = 0; e < 9; e++)
        for (int c = tid; c < H1; c += 256) W1e[e][c] = eW1[(256+e)*H1 + c];
    for (int t = tid; t < 16*544; t += 256){
        int k = t >> 4, f = t & 15;
        W2T[f][k] = (k < H1) ? f2bf(eW2[k*MD + f]) : (unsigned short)0;
    }
    for (int t = tid; t < Kk*16; t += 256){
        int n = t >> 4; int k = 528 + (t & 15);
        if (k >= H1) Hs[n][k] = 0;
    }
    if (tid < Kk){
        int j = idx_ws[node*Kk + tid];
        float d = dv_ws[node*Kk + tid];
        js[tid] = j;
        encs[tid][0] = sinf(d);
        encs[tid][1] = sinf(d*0.5f);
        encs[tid][2] = sinf(d*0.25f);
        encs[tid][3] = sinf(d*0.125f);
        encs[tid][4] = cosf(d);
        encs[tid][5] = cosf(d*0.5f);
        encs[tid][6] = cosf(d*0.25f);
        encs[tid][7] = cosf(d*0.125f);
        encs[tid][8] = d;
        int jg = (b << 11) + j;
        rels[tid][0] = coors[node*3+0] - coors[jg*3+0];
        rels[tid][1] = coors[node*3+1] - coors[jg*3+1];
        rels[tid][2] = coors[node*3+2] - coors[jg*3+2];
    }
    __syncthreads();

    // h = silu(P_i + P_j(gathered) + enc @ eW1[256:265]) -> bf16 into Hs
    for (int n = 0; n < Kk; n++){
        int jg = (b << 11) + js[n];
        const float* Qp = P + (size_t)jg*PW + H1;
        float e0=encs[n][0], e1=encs[n][1], e2=encs[n][2], e3=encs[n][3],
              e4=encs[n][4], e5=encs[n][5], e6=encs[n][6], e7=encs[n][7], e8=encs[n][8];
        for (int c = tid; c < H1; c += 256){
            float x = Pi[c] + Qp[c];
            x += e0*W1e[0][c]; x += e1*W1e[1][c]; x += e2*W1e[2][c];
            x += e3*W1e[3][c]; x += e4*W1e[4][c]; x += e5*W1e[5][c];
            x += e6*W1e[6][c]; x += e7*W1e[7][c]; x += e8*W1e[8][c];
            Hs[n][c] = f2bf(silu_f(x));
        }
    }
    __syncthreads();

    // m_raw = H(32x530) @ eW2(530x16) via MFMA 16x16x32 bf16, waves 0/1 take 16 rows each
    if (wid < 2){
        f32x4 acc = {0.f,0.f,0.f,0.f};
        int ar = wid*16 + (lane & 15);
        int kg = (lane >> 4) * 8;
        for (int s = 0; s < 17; s++){
            int k = s*32 + kg;
            s16x8 a  = *(const s16x8*)(&Hs[ar][k]);
            s16x8 bb = *(const s16x8*)(&W2T[lane & 15][k]);
            acc = __builtin_amdgcn_mfma_f32_16x16x32_bf16(a, bb, acc, 0, 0, 0);
        }
        int col = lane & 15, r0 = (lane >> 4) * 4;
        #pragma unroll
        for (int r=0;r<4;r++) m_s[wid*16 + r0 + r][col] = acc[r];
    }
    __syncthreads();
    for (int t = tid; t < Kk*MD; t += 256){
        int n = t >> 4, f = t & 15;
        m_s[n][f] = silu_f(m_s[n][f] + eb2[f]);
    }
    __syncthreads();
    if (tid < MD){
        float s = 0.f;
        for (int n=0;n<Kk;n++) s += m_s[n][tid];
        mi_ws[node*MD + tid] = s;
    }
    // cw MLP (16->64->1) per edge, 8 edges per wave; accumulate cw * rel_coors
    float ax=0.f, ay=0.f, az=0.f;
    for (int q=0;q<8;q++){
        int n = wid*8 + q;
        float acc = cb1[lane];
        #pragma unroll
        for (int f=0; f<MD; f++) acc += m_s[n][f] * cW1[f*64 + lane];
        float p = silu_f(acc) * cW2[lane];
        #pragma unroll
        for (int off=32; off; off>>=1) p += __shfl_xor(p, off);
        float cw = p + cb2[0];
        ax += cw * rels[n][0];
        ay += cw * rels[n][1];
        az += cw * rels[n][2];
    }
    if (lane == 0){ cacc[wid][0]=ax; cacc[wid][1]=ay; cacc[wid][2]=az; }
    __syncthreads();
    if (tid == 0){
        coors_out[node*3+0] = cacc[0][0]+cacc[1][0]+cacc[2][0]+cacc[3][0] + coors[node*3+0];
        coors_out[node*3+1] = cacc[0][1]+cacc[1][1]+cacc[2][1]+cacc[3][1] + coors[node*3+1];
        coors_out[node*3+2] = cacc[0][2]+cacc[1][2]+cacc[2][2]+cacc[3][2] + coors[node*3+2];
    }
}

// ---------------- Kernel D: node MLP with residual -------------------------------------------
__global__ __launch_bounds__(256) void node_kernel(const float* __restrict__ feats,
        const float* __restrict__ mi_ws,
        const float* __restrict__ nW1, const float* __restrict__ nb1,
        const float* __restrict__ nW2, const float* __restrict__ nb2,
        float* __restrict__ out){
    __shared__ float ins[8][NDI];
    __shared__ float hsd[8][NDH];
    int tid = threadIdx.x;
    int node0 = blockIdx.x * 8;
    for (int t = tid; t < 8*DIMd; t += 256) ins[t>>7][t & 127] = feats[(size_t)node0*DIMd + t];
    if (tid < 8*MD) ins[tid>>4][DIMd + (tid & 15)] = mi_ws[node0*MD + tid];
    __syncthreads();
    float acc[8];
    float bias = nb1[tid];
    #pragma unroll
    for (int m=0;m<8;m++) acc[m] = bias;
    for (int k=0;k<NDI;k++){
        float w = nW1[k*NDH + tid];
        #pragma unroll
        for (int m=0;m<8;m++) acc[m] += ins[m][k]*w;
    }
    #pragma unroll
    for (int m=0;m<8;m++) hsd[m][tid] = silu_f(acc[m]);
    __syncthreads();
    int c = tid & 127, half = tid >> 7;
    float acc2[4];
    float b2 = nb2[c];
    #pragma unroll
    for (int q=0;q<4;q++) acc2[q] = b2;
    for (int k=0;k<NDH;k++){
        float w = nW2[k*DIMd + c];
        #pragma unroll
        for (int q=0;q<4;q++) acc2[q] += hsd[half*4+q][k]*w;
    }
    #pragma unroll
    for (int q=0;q<4;q++){
        int m = half*4+q;
        out[(size_t)(node0+m)*DIMd + c] = acc2[q] + feats[(size_t)(node0+m)*DIMd + c];
    }
}

extern "C" void kernel_launch(void* const* d_in, const int* in_sizes, int n_in,
                              void* d_out, int out_size, void* d_ws, size_t ws_size,
                              hipStream_t stream){
    const float* feats = (const float*)d_in[0];
    const float* coors = (const float*)d_in[1];
    const float* eW1 = (const float*)d_in[2];
    const float* eb1 = (const float*)d_in[3];
    const float* eW2 = (const float*)d_in[4];
    const float* eb2 = (const float*)d_in[5];
    const float* cW1 = (const float*)d_in[6];
    const float* cb1 = (const float*)d_in[7];
    const float* cW2 = (const float*)d_in[8];
    const float* cb2 = (const float*)d_in[9];
    const float* nW1 = (const float*)d_in[10];
    const float* nb1 = (const float*)d_in[11];
    const float* nW2 = (const float*)d_in[12];
    const float* nb2 = (const float*)d_in[13];
    float* out = (float*)d_out;                        // node_out: 4*2048*128
    float* coors_out = out + (size_t)Bb*Nn*DIMd;       // coors_out: 4*2048*3

    char* ws = (char*)d_ws;
    int*   idx_ws = (int*)ws;                          // 1 MB
    float* dv_ws  = (float*)(ws + (1u<<20));           // 1 MB
    float* Pd     = (float*)(ws + (2u<<20));           // 8192*1060*4 = 34,734,080 B
    float* mi_ws  = (float*)(ws + (2u<<20) + 34734080u);

    topk_kernel<<<Bb*Nn, 256, 0, stream>>>(coors, idx_ws, dv_ws);
    pmat_kernel<<<dim3(Bb*Nn/16, 5), 256, 0, stream>>>(feats, eW1, eb1, Pd);
    edge_kernel<<<Bb*Nn, 256, 0, stream>>>(coors, eW1, eW2, eb2, cW1, cb1, cW2, cb2,
                                           Pd, idx_ws, dv_ws, mi_ws, coors_out);
    node_kernel<<<Bb*Nn/8, 256, 0, stream>>>(feats, mi_ws, nW1, nb1, nW2, nb2, out);
}

// Round 2
// 482.194 us; speedup vs baseline: 1.9517x; 1.9517x over previous
//
#include <hip/hip_runtime.h>
#include <hip/hip_bf16.h>
#include <math.h>

#define Bb 4
#define Nn 2048
#define DIMd 128
#define Kk 32
#define H1 530      // EDGE_IN*2
#define PW 1060     // P table width (i-part | j-part)
#define MD 16
#define NDH 256
#define NDI 144
#define HSP 568     // Hs row stride (bf16 elems): 1136B = 28-bank stride -> ~2-way

typedef float f32x4 __attribute__((ext_vector_type(4)));
typedef short s16x8 __attribute__((ext_vector_type(8)));

__device__ __forceinline__ unsigned short f2bf(float f){
    union { float f; unsigned u; } v; v.f = f;
    unsigned r = v.u + 0x7FFFu + ((v.u >> 16) & 1u);
    return (unsigned short)(r >> 16);
}
__device__ __forceinline__ float silu_f(float x){ return x / (1.0f + __expf(-x)); }

// ---------------- Kernel A: exact top-K=32 nearest (squared dist, low-index tiebreak) ----------
__global__ __launch_bounds__(256) void topk_kernel(const float* __restrict__ coors,
        int* __restrict__ idx_ws, float* __restrict__ dv_ws){
    __shared__ float dist[Nn];
    __shared__ float rd[4]; __shared__ int rj[4]; __shared__ int sel;
    int node = blockIdx.x; int b = node >> 11;
    int tid = threadIdx.x;
    const float* cbp = coors + (size_t)b * Nn * 3;
    float cx = coors[node*3+0], cy = coors[node*3+1], cz = coors[node*3+2];
    for (int j = tid; j < Nn; j += 256){
        float dx = cx - cbp[j*3+0], dy = cy - cbp[j*3+1], dz = cz - cbp[j*3+2];
        dist[j] = dx*dx + dy*dy + dz*dz;
    }
    __syncthreads();
    float md = 3.4e38f; int mj = 0x7fffffff;
    #pragma unroll
    for (int t=0;t<8;t++){ int j = tid + t*256; float d = dist[j]; if (d < md){ md=d; mj=j; } }
    for (int r = 0; r < Kk; r++){
        float d = md; int j = mj;
        #pragma unroll
        for (int off=32; off; off>>=1){
            float d2 = __shfl_xor(d, off); int j2 = __shfl_xor(j, off);
            if (d2 < d || (d2 == d && j2 < j)){ d = d2; j = j2; }
        }
        if ((tid & 63) == 0){ rd[tid>>6] = d; rj[tid>>6] = j; }
        __syncthreads();
        if (tid == 0){
            float bd = rd[0]; int bj = rj[0];
            for (int w=1; w<4; w++) if (rd[w] < bd || (rd[w]==bd && rj[w]<bj)){ bd=rd[w]; bj=rj[w]; }
            idx_ws[node*Kk + r] = bj;
            dv_ws[node*Kk + r] = bd;
            dist[bj] = 3.4e38f;
            sel = bj;
        }
        __syncthreads();
        if ((sel & 255) == tid){   // owner of the removed element rescans its 8 slots
            md = 3.4e38f; mj = 0x7fffffff;
            #pragma unroll
            for (int t=0;t<8;t++){ int j2 = tid + t*256; float dd = dist[j2]; if (dd < md){ md=dd; mj=j2; } }
        }
    }
}

// ---------------- Kernel B: P[node][0:530]=feats@eW1_i+eb1 ; P[node][530:1060]=feats@eW1_j ----
__global__ __launch_bounds__(256) void pmat_kernel(const float* __restrict__ feats,
        const float* __restrict__ eW1, const float* __restrict__ eb1,
        float* __restrict__ P){
    __shared__ float fs[16][128];
    int tid = threadIdx.x;
    int node0 = blockIdx.x * 16;
    for (int t = tid; t < 16*128; t += 256) fs[t>>7][t&127] = feats[(size_t)node0*DIMd + t];
    __syncthreads();
    int c = blockIdx.y * 256 + tid;
    if (c >= PW) return;
    int col, rbase; float bias;
    if (c < H1){ col = c; rbase = 0; bias = eb1[c]; }
    else { col = c - H1; rbase = 128; bias = 0.f; }
    float acc[16];
    #pragma unroll
    for (int m=0;m<16;m++) acc[m] = bias;
    for (int k=0;k<128;k++){
        float w = eW1[(rbase+k)*H1 + col];
        #pragma unroll
        for (int m=0;m<16;m++) acc[m] += fs[m][k]*w;
    }
    #pragma unroll
    for (int m=0;m<16;m++) P[(size_t)(node0+m)*PW + c] = acc[m];
}

// ---------------- Kernel B2: precompute eW2 MFMA B-fragments, bf16, fragment-linear ----------
// W2F[s*64*8 + lane*8 + j] = bf16(eW2[k][col]), k = s*32 + (lane>>4)*8 + j, col = lane&15, 0 if k>=530
__global__ __launch_bounds__(256) void w2frag_kernel(const float* __restrict__ eW2,
        unsigned short* __restrict__ W2F){
    int t = threadIdx.x;
    for (int i = t; i < 17*64*8; i += 256){
        int j = i & 7;
        int lane = (i >> 3) & 63;
        int s = i >> 9;
        int k = s*32 + ((lane >> 4) << 3) + j;
        int col = lane & 15;
        W2F[i] = (k < H1) ? f2bf(eW2[k*MD + col]) : (unsigned short)0;
    }
}

// ---------------- Kernel C: per-node edge pipeline -------------------------------------------
__global__ __launch_bounds__(256, 4) void edge_kernel(const float* __restrict__ coors,
        const float* __restrict__ eW1, const float* __restrict__ eb2,
        const float* __restrict__ cW1, const float* __restrict__ cb1,
        const float* __restrict__ cW2, const float* __restrict__ cb2,
        const float* __restrict__ P, const unsigned short* __restrict__ W2F,
        const int* __restrict__ idx_ws, const float* __restrict__ dv_ws,
        float* __restrict__ mi_ws, float* __restrict__ coors_out){
    __shared__ float encs[Kk][9];
    __shared__ float rels[Kk][3];
    __shared__ int js[Kk];
    __shared__ unsigned short Hs[Kk][HSP];   // bf16, K padded (cols 530..543 zeroed)
    __shared__ float m_s[Kk][MD];
    __shared__ float cacc[4][3];
    int node = blockIdx.x; int tid = threadIdx.x;
    int b = node >> 11;
    int wid = tid >> 6, lane = tid & 63;
    bool has3 = (tid < H1 - 512);   // tid < 18

    // zero the MFMA K-pad region (cols 528..543; 528/529 overwritten below)
    for (int t = tid; t < Kk*16; t += 256){
        int n = t >> 4; Hs[n][528 + (t & 15)] = 0;
    }
    // register-cache Pi and the 9 encoding rows of eW1 for this thread's columns
    const float* Pn = P + (size_t)node*PW;
    float pi0 = Pn[tid], pi1 = Pn[tid+256], pi2 = has3 ? Pn[tid+512] : 0.f;
    float w1a[9], w1b[9], w1c[9];
    #pragma unroll
    for (int q=0;q<9;q++){
        const float* wr = eW1 + (size_t)(256+q)*H1;
        w1a[q] = wr[tid]; w1b[q] = wr[tid+256]; w1c[q] = has3 ? wr[tid+512] : 0.f;
    }
    if (tid < Kk){
        int j = idx_ws[node*Kk + tid];
        float d = dv_ws[node*Kk + tid];
        js[tid] = j;
        encs[tid][0] = sinf(d);
        encs[tid][1] = sinf(d*0.5f);
        encs[tid][2] = sinf(d*0.25f);
        encs[tid][3] = sinf(d*0.125f);
        encs[tid][4] = cosf(d);
        encs[tid][5] = cosf(d*0.5f);
        encs[tid][6] = cosf(d*0.25f);
        encs[tid][7] = cosf(d*0.125f);
        encs[tid][8] = d;
        int jg = (b << 11) + j;
        rels[tid][0] = coors[node*3+0] - coors[jg*3+0];
        rels[tid][1] = coors[node*3+1] - coors[jg*3+1];
        rels[tid][2] = coors[node*3+2] - coors[jg*3+2];
    }
    __syncthreads();

    // h = silu(P_i + P_j(gathered) + enc @ eW1[256:265]) -> bf16 into Hs
    for (int n = 0; n < Kk; n++){
        int jg = (b << 11) + js[n];
        const float* Qp = P + (size_t)jg*PW + H1;
        float e0=encs[n][0], e1=encs[n][1], e2=encs[n][2], e3=encs[n][3],
              e4=encs[n][4], e5=encs[n][5], e6=encs[n][6], e7=encs[n][7], e8=encs[n][8];
        float q0 = Qp[tid], q1 = Qp[tid+256];
        float q2 = has3 ? Qp[tid+512] : 0.f;
        float x0 = pi0 + q0, x1 = pi1 + q1, x2 = pi2 + q2;
        x0 += e0*w1a[0]+e1*w1a[1]+e2*w1a[2]+e3*w1a[3]+e4*w1a[4]+e5*w1a[5]+e6*w1a[6]+e7*w1a[7]+e8*w1a[8];
        x1 += e0*w1b[0]+e1*w1b[1]+e2*w1b[2]+e3*w1b[3]+e4*w1b[4]+e5*w1b[5]+e6*w1b[6]+e7*w1b[7]+e8*w1b[8];
        x2 += e0*w1c[0]+e1*w1c[1]+e2*w1c[2]+e3*w1c[3]+e4*w1c[4]+e5*w1c[5]+e6*w1c[6]+e7*w1c[7]+e8*w1c[8];
        Hs[n][tid]      = f2bf(silu_f(x0));
        Hs[n][tid+256]  = f2bf(silu_f(x1));
        if (has3) Hs[n][tid+512] = f2bf(silu_f(x2));
    }
    __syncthreads();

    // m_raw = H(32x530) @ eW2(530x16) via MFMA 16x16x32 bf16, waves 0/1: 16 rows each
    if (wid < 2){
        f32x4 acc = {0.f,0.f,0.f,0.f};
        int ar = wid*16 + (lane & 15);
        int kg = (lane >> 4) * 8;
        const s16x8* W2Fv = (const s16x8*)W2F;
        for (int s = 0; s < 17; s++){
            s16x8 a  = *(const s16x8*)(&Hs[ar][s*32 + kg]);
            s16x8 bb = W2Fv[s*64 + lane];
            acc = __builtin_amdgcn_mfma_f32_16x16x32_bf16(a, bb, acc, 0, 0, 0);
        }
        int col = lane & 15, r0 = (lane >> 4) * 4;
        #pragma unroll
        for (int r=0;r<4;r++) m_s[wid*16 + r0 + r][col] = acc[r];
    }
    __syncthreads();
    for (int t = tid; t < Kk*MD; t += 256){
        int n = t >> 4, f = t & 15;
        m_s[n][f] = silu_f(m_s[n][f] + eb2[f]);
    }
    __syncthreads();
    if (tid < MD){
        float s = 0.f;
        for (int n=0;n<Kk;n++) s += m_s[n][tid];
        mi_ws[node*MD + tid] = s;
    }
    // cw MLP (16->64->1) per edge, 8 edges per wave; accumulate cw * rel_coors
    float ax=0.f, ay=0.f, az=0.f;
    for (int q=0;q<8;q++){
        int n = wid*8 + q;
        float acc = cb1[lane];
        #pragma unroll
        for (int f=0; f<MD; f++) acc += m_s[n][f] * cW1[f*64 + lane];
        float p = silu_f(acc) * cW2[lane];
        #pragma unroll
        for (int off=32; off; off>>=1) p += __shfl_xor(p, off);
        float cw = p + cb2[0];
        ax += cw * rels[n][0];
        ay += cw * rels[n][1];
        az += cw * rels[n][2];
    }
    if (lane == 0){ cacc[wid][0]=ax; cacc[wid][1]=ay; cacc[wid][2]=az; }
    __syncthreads();
    if (tid == 0){
        coors_out[node*3+0] = cacc[0][0]+cacc[1][0]+cacc[2][0]+cacc[3][0] + coors[node*3+0];
        coors_out[node*3+1] = cacc[0][1]+cacc[1][1]+cacc[2][1]+cacc[3][1] + coors[node*3+1];
        coors_out[node*3+2] = cacc[0][2]+cacc[1][2]+cacc[2][2]+cacc[3][2] + coors[node*3+2];
    }
}

// ---------------- Kernel D: node MLP with residual -------------------------------------------
__global__ __launch_bounds__(256) void node_kernel(const float* __restrict__ feats,
        const float* __restrict__ mi_ws,
        const float* __restrict__ nW1, const float* __restrict__ nb1,
        const float* __restrict__ nW2, const float* __restrict__ nb2,
        float* __restrict__ out){
    __shared__ float ins[8][NDI];
    __shared__ float hsd[8][NDH];
    int tid = threadIdx.x;
    int node0 = blockIdx.x * 8;
    for (int t = tid; t < 8*DIMd; t += 256) ins[t>>7][t & 127] = feats[(size_t)node0*DIMd + t];
    if (tid < 8*MD) ins[tid>>4][DIMd + (tid & 15)] = mi_ws[node0*MD + tid];
    __syncthreads();
    float acc[8];
    float bias = nb1[tid];
    #pragma unroll
    for (int m=0;m<8;m++) acc[m] = bias;
    for (int k=0;k<NDI;k++){
        float w = nW1[k*NDH + tid];
        #pragma unroll
        for (int m=0;m<8;m++) acc[m] += ins[m][k]*w;
    }
    #pragma unroll
    for (int m=0;m<8;m++) hsd[m][tid] = silu_f(acc[m]);
    __syncthreads();
    int c = tid & 127, half = tid >> 7;
    float acc2[4];
    float b2 = nb2[c];
    #pragma unroll
    for (int q=0;q<4;q++) acc2[q] = b2;
    for (int k=0;k<NDH;k++){
        float w = nW2[k*DIMd + c];
        #pragma unroll
        for (int q=0;q<4;q++) acc2[q] += hsd[half*4+q][k]*w;
    }
    #pragma unroll
    for (int q=0;q<4;q++){
        int m = half*4+q;
        out[(size_t)(node0+m)*DIMd + c] = acc2[q] + feats[(size_t)(node0+m)*DIMd + c];
    }
}

extern "C" void kernel_launch(void* const* d_in, const int* in_sizes, int n_in,
                              void* d_out, int out_size, void* d_ws, size_t ws_size,
                              hipStream_t stream){
    const float* feats = (const float*)d_in[0];
    const float* coors = (const float*)d_in[1];
    const float* eW1 = (const float*)d_in[2];
    const float* eb1 = (const float*)d_in[3];
    const float* eW2 = (const float*)d_in[4];
    const float* eb2 = (const float*)d_in[5];
    const float* cW1 = (const float*)d_in[6];
    const float* cb1 = (const float*)d_in[7];
    const float* cW2 = (const float*)d_in[8];
    const float* cb2 = (const float*)d_in[9];
    const float* nW1 = (const float*)d_in[10];
    const float* nb1 = (const float*)d_in[11];
    const float* nW2 = (const float*)d_in[12];
    const float* nb2 = (const float*)d_in[13];
    float* out = (float*)d_out;                        // node_out: 4*2048*128
    float* coors_out = out + (size_t)Bb*Nn*DIMd;       // coors_out: 4*2048*3

    char* ws = (char*)d_ws;
    int*   idx_ws = (int*)ws;                          // 1 MB
    float* dv_ws  = (float*)(ws + (1u<<20));           // 1 MB
    float* Pd     = (float*)(ws + (2u<<20));           // 8192*1060*4 = 34,734,080 B
    float* mi_ws  = (float*)(ws + (2u<<20) + 34734080u);          // 512 KB
    unsigned short* W2F = (unsigned short*)(ws + (2u<<20) + 34734080u + 524288u); // 17.4 KB

    topk_kernel<<<Bb*Nn, 256, 0, stream>>>(coors, idx_ws, dv_ws);
    pmat_kernel<<<dim3(Bb*Nn/16, 5), 256, 0, stream>>>(feats, eW1, eb1, Pd);
    w2frag_kernel<<<1, 256, 0, stream>>>(eW2, W2F);
    edge_kernel<<<Bb*Nn, 256, 0, stream>>>(coors, eW1, eb2, cW1, cb1, cW2, cb2,
                                           Pd, W2F, idx_ws, dv_ws, mi_ws, coors_out);
    node_kernel<<<Bb*Nn/8, 256, 0, stream>>>(feats, mi_ws, nW1, nb1, nW2, nb2, out);
}

// Round 3
// 426.366 us; speedup vs baseline: 2.2073x; 1.1309x over previous
//
#include <hip/hip_runtime.h>
#include <hip/hip_bf16.h>
#include <math.h>

#define Bb 4
#define Nn 2048
#define DIMd 128
#define Kk 32
#define H1 530      // EDGE_IN*2
#define PW 1060     // P table width (i-part | j-part)
#define MD 16
#define NDH 256
#define NDI 144
#define HSP 568     // Hs row stride (bf16 elems)

typedef float f32x2 __attribute__((ext_vector_type(2)));
typedef float f32x4 __attribute__((ext_vector_type(4)));
typedef short s16x8 __attribute__((ext_vector_type(8)));

__device__ __forceinline__ unsigned short f2bf(float f){
    union { float f; unsigned u; } v; v.f = f;
    unsigned r = v.u + 0x7FFFu + ((v.u >> 16) & 1u);
    return (unsigned short)(r >> 16);
}
__device__ __forceinline__ float silu_f(float x){
    float e = __builtin_amdgcn_exp2f(x * -1.442695041f);
    return x * __builtin_amdgcn_rcpf(1.0f + e);
}
__device__ __forceinline__ f32x2 silu2(f32x2 x){
    float e0 = __builtin_amdgcn_exp2f(x[0] * -1.442695041f);
    float e1 = __builtin_amdgcn_exp2f(x[1] * -1.442695041f);
    f32x2 r;
    r[0] = x[0] * __builtin_amdgcn_rcpf(1.0f + e0);
    r[1] = x[1] * __builtin_amdgcn_rcpf(1.0f + e1);
    return r;
}
__device__ __forceinline__ unsigned cvt_pk_bf16(float a, float b){
    unsigned r;
    asm("v_cvt_pk_bf16_f32 %0, %1, %2" : "=v"(r) : "v"(a), "v"(b));
    return r;
}

// ---------------- Kernel A: exact top-K=32, one wave per node, zero barriers ------------------
// Lane owns 32 dists in registers; 32 rounds of 64-lane butterfly argmin (lex (d, j) order,
// low index wins ties == lax.top_k semantics); winner-owning lane re-scans with static indices.
__global__ __launch_bounds__(256) void topk_kernel(const float* __restrict__ coors,
        int* __restrict__ idx_ws, float* __restrict__ dv_ws){
    int tid = threadIdx.x;
    int w = tid >> 6, lane = tid & 63;
    int node = blockIdx.x * 4 + w;
    int b = node >> 11;
    const float* cbp = coors + (size_t)b * Nn * 3;
    float cx = coors[node*3+0], cy = coors[node*3+1], cz = coors[node*3+2];
    float d[32];
    #pragma unroll
    for (int t = 0; t < 32; t++){
        int j = t*64 + lane;
        float dx = cx - cbp[j*3+0], dy = cy - cbp[j*3+1], dz = cz - cbp[j*3+2];
        d[t] = dx*dx + dy*dy + dz*dz;
    }
    float md = d[0]; int mj = lane;
    #pragma unroll
    for (int t = 1; t < 32; t++){
        int jt = t*64 + lane;
        if (d[t] < md){ md = d[t]; mj = jt; }   // strict < keeps lowest index
    }
    for (int r = 0; r < Kk; r++){
        float bd = md; int bj = mj;
        #pragma unroll
        for (int off = 32; off; off >>= 1){
            float d2 = __shfl_xor(bd, off); int j2 = __shfl_xor(bj, off);
            if (d2 < bd || (d2 == bd && j2 < bj)){ bd = d2; bj = j2; }
        }
        if (lane == 0){
            idx_ws[node*Kk + r] = bj;
            dv_ws[node*Kk + r] = bd;
        }
        if (mj == bj){   // exactly one lane owns the winner: remove + rescan, static idx only
            md = 3.4e38f; mj = 0x7fffffff;
            #pragma unroll
            for (int t = 0; t < 32; t++){
                int jt = t*64 + lane;
                if (jt == bj) d[t] = 3.4e38f;
                if (d[t] < md){ md = d[t]; mj = jt; }
            }
        }
    }
}

// ---------------- Kernel B: P = feats @ eW1 (i-part+bias | j-part), packed-f32 ---------------
__global__ __launch_bounds__(256) void pmat_kernel(const float* __restrict__ feats,
        const float* __restrict__ eW1, const float* __restrict__ eb1,
        float* __restrict__ P){
    __shared__ float fsT[128][20];   // [k][m], pad 20 -> 16B-aligned rows, spread banks
    int tid = threadIdx.x;
    int node0 = blockIdx.x * 16;
    for (int t = tid; t < 16*128; t += 256){
        int m = t >> 7, k = t & 127;
        fsT[k][m] = feats[(size_t)node0*DIMd + t];
    }
    __syncthreads();
    // column-pair slots: A = pair tid (P cols 2t,2t+1), B = pair 256+tid, C = pair 512+tid (tid<18)
    bool hasC = tid < 18;
    int cA = 2*tid;            // 0..510   (i-part)
    int cB = 512 + 2*tid;      // 512..1022 (i-part if <530 else j-part)
    int cC = 1024 + 2*tid;     // 1024..1058 (j-part)
    const float* wpA = eW1 + cA;
    const float* wpB = (cB < H1) ? (eW1 + cB) : (eW1 + (size_t)128*H1 + (cB - H1));
    const float* wpC = eW1 + (size_t)128*H1 + (cC - H1);
    f32x2 accA[16], accB[16], accC[16];
    #pragma unroll
    for (int m=0;m<16;m++){ accA[m]=(f32x2){0,0}; accB[m]=(f32x2){0,0}; accC[m]=(f32x2){0,0}; }
    for (int k = 0; k < 128; k++){
        f32x4 f0 = *(const f32x4*)&fsT[k][0];
        f32x4 f1 = *(const f32x4*)&fsT[k][4];
        f32x4 f2 = *(const f32x4*)&fsT[k][8];
        f32x4 f3 = *(const f32x4*)&fsT[k][12];
        f32x2 wA = *(const f32x2*)(wpA + (size_t)k*H1);
        f32x2 wB = *(const f32x2*)(wpB + (size_t)k*H1);
        #pragma unroll
        for (int m=0;m<4;m++){
            f32x2 s0 = {f0[m],f0[m]}, s1 = {f1[m],f1[m]}, s2 = {f2[m],f2[m]}, s3 = {f3[m],f3[m]};
            accA[m]    += s0*wA;  accB[m]    += s0*wB;
            accA[4+m]  += s1*wA;  accB[4+m]  += s1*wB;
            accA[8+m]  += s2*wA;  accB[8+m]  += s2*wB;
            accA[12+m] += s3*wA;  accB[12+m] += s3*wB;
        }
        if (hasC){
            f32x2 wC = *(const f32x2*)(wpC + (size_t)k*H1);
            #pragma unroll
            for (int m=0;m<4;m++){
                accC[m]    += (f32x2){f0[m],f0[m]}*wC;
                accC[4+m]  += (f32x2){f1[m],f1[m]}*wC;
                accC[8+m]  += (f32x2){f2[m],f2[m]}*wC;
                accC[12+m] += (f32x2){f3[m],f3[m]}*wC;
            }
        }
    }
    f32x2 bA = *(const f32x2*)(eb1 + cA);
    f32x2 bB = (cB < H1) ? *(const f32x2*)(eb1 + cB) : (f32x2){0,0};
    #pragma unroll
    for (int m=0;m<16;m++){
        float* Pr = P + (size_t)(node0+m)*PW;
        *(f32x2*)(Pr + cA) = accA[m] + bA;
        *(f32x2*)(Pr + cB) = accB[m] + bB;
        if (hasC) *(f32x2*)(Pr + cC) = accC[m];
    }
}

// ---------------- Kernel B2: precompute eW2 MFMA B-fragments, bf16, fragment-linear ----------
__global__ __launch_bounds__(256) void w2frag_kernel(const float* __restrict__ eW2,
        unsigned short* __restrict__ W2F){
    int t = threadIdx.x;
    for (int i = t; i < 17*64*8; i += 256){
        int j = i & 7;
        int lane = (i >> 3) & 63;
        int s = i >> 9;
        int k = s*32 + ((lane >> 4) << 3) + j;
        int col = lane & 15;
        W2F[i] = (k < H1) ? f2bf(eW2[k*MD + col]) : (unsigned short)0;
    }
}

// ---------------- Kernel C: per-node edge pipeline, packed-f32 h-phase -----------------------
__global__ __launch_bounds__(256, 4) void edge_kernel(const float* __restrict__ coors,
        const float* __restrict__ eW1, const float* __restrict__ eb2,
        const float* __restrict__ cW1, const float* __restrict__ cb1,
        const float* __restrict__ cW2, const float* __restrict__ cb2,
        const float* __restrict__ P, const unsigned short* __restrict__ W2F,
        const int* __restrict__ idx_ws, const float* __restrict__ dv_ws,
        float* __restrict__ mi_ws, float* __restrict__ coors_out){
    __shared__ float encs[Kk][12];   // 9 used, pad 12 -> 16B rows for b128 reads
    __shared__ float rels[Kk][3];
    __shared__ int js[Kk];
    __shared__ unsigned short Hs[Kk][HSP];
    __shared__ float m_s[Kk][MD];
    __shared__ float cacc[4][3];
    int node = blockIdx.x; int tid = threadIdx.x;
    int b = node >> 11;
    int wid = tid >> 6, lane = tid & 63;
    bool hasB = tid < 9;   // column pairs 256+tid -> cols 512..529

    for (int t = tid; t < Kk*16; t += 256){
        int n = t >> 4; Hs[n][528 + (t & 15)] = 0;
    }
    // register-cache Pi pair + 9 enc weight rows as f32x2 pairs
    const float* Pn = P + (size_t)node*PW;
    f32x2 piA = *(const f32x2*)(Pn + 2*tid);
    f32x2 piB = hasB ? *(const f32x2*)(Pn + 512 + 2*tid) : (f32x2){0,0};
    f32x2 w1A[9], w1B[9];
    #pragma unroll
    for (int q=0;q<9;q++){
        const float* wr = eW1 + (size_t)(256+q)*H1;
        w1A[q] = *(const f32x2*)(wr + 2*tid);
        w1B[q] = hasB ? *(const f32x2*)(wr + 512 + 2*tid) : (f32x2){0,0};
    }
    if (tid < Kk){
        int j = idx_ws[node*Kk + tid];
        float dv = dv_ws[node*Kk + tid];
        js[tid] = j;
        encs[tid][0] = sinf(dv);
        encs[tid][1] = sinf(dv*0.5f);
        encs[tid][2] = sinf(dv*0.25f);
        encs[tid][3] = sinf(dv*0.125f);
        encs[tid][4] = cosf(dv);
        encs[tid][5] = cosf(dv*0.5f);
        encs[tid][6] = cosf(dv*0.25f);
        encs[tid][7] = cosf(dv*0.125f);
        encs[tid][8] = dv;
        int jg = (b << 11) + j;
        rels[tid][0] = coors[node*3+0] - coors[jg*3+0];
        rels[tid][1] = coors[node*3+1] - coors[jg*3+1];
        rels[tid][2] = coors[node*3+2] - coors[jg*3+2];
    }
    __syncthreads();

    // h = silu(P_i + P_j(gathered) + enc @ eW1[256:265]) -> bf16 into Hs (packed pairs)
    for (int n = 0; n < Kk; n++){
        int jg = (b << 11) + js[n];
        const float* Qp = P + (size_t)jg*PW + H1;
        f32x4 e03 = *(const f32x4*)&encs[n][0];
        f32x4 e47 = *(const f32x4*)&encs[n][4];
        float e8 = encs[n][8];
        f32x2 xA = piA + *(const f32x2*)(Qp + 2*tid);
        xA += (f32x2){e03[0],e03[0]} * w1A[0];
        xA += (f32x2){e03[1],e03[1]} * w1A[1];
        xA += (f32x2){e03[2],e03[2]} * w1A[2];
        xA += (f32x2){e03[3],e03[3]} * w1A[3];
        xA += (f32x2){e47[0],e47[0]} * w1A[4];
        xA += (f32x2){e47[1],e47[1]} * w1A[5];
        xA += (f32x2){e47[2],e47[2]} * w1A[6];
        xA += (f32x2){e47[3],e47[3]} * w1A[7];
        xA += (f32x2){e8,e8} * w1A[8];
        xA = silu2(xA);
        *(unsigned*)&Hs[n][2*tid] = cvt_pk_bf16(xA[0], xA[1]);
        if (hasB){
            f32x2 xB = piB + *(const f32x2*)(Qp + 512 + 2*tid);
            xB += (f32x2){e03[0],e03[0]} * w1B[0];
            xB += (f32x2){e03[1],e03[1]} * w1B[1];
            xB += (f32x2){e03[2],e03[2]} * w1B[2];
            xB += (f32x2){e03[3],e03[3]} * w1B[3];
            xB += (f32x2){e47[0],e47[0]} * w1B[4];
            xB += (f32x2){e47[1],e47[1]} * w1B[5];
            xB += (f32x2){e47[2],e47[2]} * w1B[6];
            xB += (f32x2){e47[3],e47[3]} * w1B[7];
            xB += (f32x2){e8,e8} * w1B[8];
            xB = silu2(xB);
            *(unsigned*)&Hs[n][512 + 2*tid] = cvt_pk_bf16(xB[0], xB[1]);
        }
    }
    __syncthreads();

    // m_raw = H(32x530) @ eW2(530x16) via MFMA 16x16x32 bf16
    if (wid < 2){
        f32x4 acc = {0.f,0.f,0.f,0.f};
        int ar = wid*16 + (lane & 15);
        int kg = (lane >> 4) * 8;
        const s16x8* W2Fv = (const s16x8*)W2F;
        for (int s = 0; s < 17; s++){
            s16x8 a  = *(const s16x8*)(&Hs[ar][s*32 + kg]);
            s16x8 bb = W2Fv[s*64 + lane];
            acc = __builtin_amdgcn_mfma_f32_16x16x32_bf16(a, bb, acc, 0, 0, 0);
        }
        int col = lane & 15, r0 = (lane >> 4) * 4;
        #pragma unroll
        for (int r=0;r<4;r++) m_s[wid*16 + r0 + r][col] = acc[r];
    }
    __syncthreads();
    for (int t = tid; t < Kk*MD; t += 256){
        int n = t >> 4, f = t & 15;
        m_s[n][f] = silu_f(m_s[n][f] + eb2[f]);
    }
    __syncthreads();
    if (tid < MD){
        float s = 0.f;
        for (int n=0;n<Kk;n++) s += m_s[n][tid];
        mi_ws[node*MD + tid] = s;
    }
    // cw MLP (16->64->1) per edge, 8 edges per wave; accumulate cw * rel_coors
    float ax=0.f, ay=0.f, az=0.f;
    for (int q=0;q<8;q++){
        int n = wid*8 + q;
        float acc = cb1[lane];
        #pragma unroll
        for (int f=0; f<MD; f++) acc += m_s[n][f] * cW1[f*64 + lane];
        float p = silu_f(acc) * cW2[lane];
        #pragma unroll
        for (int off=32; off; off>>=1) p += __shfl_xor(p, off);
        float cw = p + cb2[0];
        ax += cw * rels[n][0];
        ay += cw * rels[n][1];
        az += cw * rels[n][2];
    }
    if (lane == 0){ cacc[wid][0]=ax; cacc[wid][1]=ay; cacc[wid][2]=az; }
    __syncthreads();
    if (tid == 0){
        coors_out[node*3+0] = cacc[0][0]+cacc[1][0]+cacc[2][0]+cacc[3][0] + coors[node*3+0];
        coors_out[node*3+1] = cacc[0][1]+cacc[1][1]+cacc[2][1]+cacc[3][1] + coors[node*3+1];
        coors_out[node*3+2] = cacc[0][2]+cacc[1][2]+cacc[2][2]+cacc[3][2] + coors[node*3+2];
    }
}

// ---------------- Kernel D: node MLP with residual, packed-f32 -------------------------------
__global__ __launch_bounds__(256) void node_kernel(const float* __restrict__ feats,
        const float* __restrict__ mi_ws,
        const float* __restrict__ nW1, const float* __restrict__ nb1,
        const float* __restrict__ nW2, const float* __restrict__ nb2,
        float* __restrict__ out){
    __shared__ float insT[NDI][12];   // [k][m], pad 12
    __shared__ float hsdT[NDH][12];
    int tid = threadIdx.x;
    int node0 = blockIdx.x * 8;
    for (int t = tid; t < 8*DIMd; t += 256){
        int m = t >> 7, k = t & 127;
        insT[k][m] = feats[(size_t)node0*DIMd + t];
    }
    if (tid < 8*MD) insT[DIMd + (tid & 15)][tid >> 4] = mi_ws[node0*MD + tid];
    __syncthreads();
    // layer 1: hidden unit = tid, 8 nodes as 4 f32x2 pairs
    float bias = nb1[tid];
    f32x2 acc[4];
    #pragma unroll
    for (int p=0;p<4;p++) acc[p] = (f32x2){bias, bias};
    for (int k = 0; k < NDI; k++){
        float wv = nW1[(size_t)k*NDH + tid];
        f32x2 w2 = {wv, wv};
        acc[0] += *(const f32x2*)&insT[k][0] * w2;
        acc[1] += *(const f32x2*)&insT[k][2] * w2;
        acc[2] += *(const f32x2*)&insT[k][4] * w2;
        acc[3] += *(const f32x2*)&insT[k][6] * w2;
    }
    #pragma unroll
    for (int p=0;p<4;p++) *(f32x2*)&hsdT[tid][2*p] = silu2(acc[p]);
    __syncthreads();
    // layer 2: c = tid&127, half = tid>>7 handles nodes half*4..half*4+3 as 2 pairs
    int c = tid & 127, half = tid >> 7;
    float b2 = nb2[c];
    f32x2 a0 = {b2, b2}, a1 = {b2, b2};
    for (int k = 0; k < NDH; k++){
        float wv = nW2[(size_t)k*DIMd + c];
        f32x2 w2 = {wv, wv};
        a0 += *(const f32x2*)&hsdT[k][half*4]     * w2;
        a1 += *(const f32x2*)&hsdT[k][half*4 + 2] * w2;
    }
    #pragma unroll
    for (int q=0;q<4;q++){
        int m = half*4 + q;
        float v = (q < 2) ? a0[q & 1] : a1[q & 1];
        out[(size_t)(node0+m)*DIMd + c] = v + feats[(size_t)(node0+m)*DIMd + c];
    }
}

extern "C" void kernel_launch(void* const* d_in, const int* in_sizes, int n_in,
                              void* d_out, int out_size, void* d_ws, size_t ws_size,
                              hipStream_t stream){
    const float* feats = (const float*)d_in[0];
    const float* coors = (const float*)d_in[1];
    const float* eW1 = (const float*)d_in[2];
    const float* eb1 = (const float*)d_in[3];
    const float* eW2 = (const float*)d_in[4];
    const float* eb2 = (const float*)d_in[5];
    const float* cW1 = (const float*)d_in[6];
    const float* cb1 = (const float*)d_in[7];
    const float* cW2 = (const float*)d_in[8];
    const float* cb2 = (const float*)d_in[9];
    const float* nW1 = (const float*)d_in[10];
    const float* nb1 = (const float*)d_in[11];
    const float* nW2 = (const float*)d_in[12];
    const float* nb2 = (const float*)d_in[13];
    float* out = (float*)d_out;                        // node_out: 4*2048*128
    float* coors_out = out + (size_t)Bb*Nn*DIMd;       // coors_out: 4*2048*3

    char* ws = (char*)d_ws;
    int*   idx_ws = (int*)ws;                          // 1 MB
    float* dv_ws  = (float*)(ws + (1u<<20));           // 1 MB
    float* Pd     = (float*)(ws + (2u<<20));           // 8192*1060*4 = 34,734,080 B
    float* mi_ws  = (float*)(ws + (2u<<20) + 34734080u);          // 512 KB
    unsigned short* W2F = (unsigned short*)(ws + (2u<<20) + 34734080u + 524288u); // 17.4 KB

    topk_kernel<<<Bb*Nn/4, 256, 0, stream>>>(coors, idx_ws, dv_ws);
    pmat_kernel<<<Bb*Nn/16, 256, 0, stream>>>(feats, eW1, eb1, Pd);
    w2frag_kernel<<<1, 256, 0, stream>>>(eW2, W2F);
    edge_kernel<<<Bb*Nn, 256, 0, stream>>>(coors, eW1, eb2, cW1, cb1, cW2, cb2,
                                           Pd, W2F, idx_ws, dv_ws, mi_ws, coors_out);
    node_kernel<<<Bb*Nn/8, 256, 0, stream>>>(feats, mi_ws, nW1, nb1, nW2, nb2, out);
}

// Round 4
// 304.953 us; speedup vs baseline: 3.0861x; 1.3981x over previous
//
#include <hip/hip_runtime.h>
#include <hip/hip_bf16.h>
#include <math.h>

#define Bb 4
#define Nn 2048
#define DIMd 128
#define Kk 32
#define H1 530      // EDGE_IN*2
#define PW2 530     // P table width (i-part only)
#define MD 16
#define NDH 256
#define NDI 144
#define HSP 552     // Hs row stride (bf16): 1104B row, 16B-aligned, 2-way bank

typedef float f32x2 __attribute__((ext_vector_type(2)));
typedef float f32x4 __attribute__((ext_vector_type(4)));
typedef short s16x8 __attribute__((ext_vector_type(8)));

__device__ __forceinline__ unsigned short f2bf(float f){
    union { float f; unsigned u; } v; v.f = f;
    unsigned r = v.u + 0x7FFFu + ((v.u >> 16) & 1u);
    return (unsigned short)(r >> 16);
}
__device__ __forceinline__ float silu_f(float x){
    float e = __builtin_amdgcn_exp2f(x * -1.442695041f);
    return x * __builtin_amdgcn_rcpf(1.0f + e);
}
__device__ __forceinline__ f32x2 silu2(f32x2 x){
    float e0 = __builtin_amdgcn_exp2f(x[0] * -1.442695041f);
    float e1 = __builtin_amdgcn_exp2f(x[1] * -1.442695041f);
    f32x2 r;
    r[0] = x[0] * __builtin_amdgcn_rcpf(1.0f + e0);
    r[1] = x[1] * __builtin_amdgcn_rcpf(1.0f + e1);
    return r;
}
__device__ __forceinline__ unsigned cvt_pk_bf16(float a, float b){
    unsigned r;
    asm("v_cvt_pk_bf16_f32 %0, %1, %2" : "=v"(r) : "v"(a), "v"(b));
    return r;
}

// ---------------- Kernel A: exact top-K=32, one wave per node, zero barriers ------------------
__global__ __launch_bounds__(256) void topk_kernel(const float* __restrict__ coors,
        int* __restrict__ idx_ws, float* __restrict__ dv_ws){
    int tid = threadIdx.x;
    int w = tid >> 6, lane = tid & 63;
    int node = blockIdx.x * 4 + w;
    int b = node >> 11;
    const float* cbp = coors + (size_t)b * Nn * 3;
    float cx = coors[node*3+0], cy = coors[node*3+1], cz = coors[node*3+2];
    float d[32];
    #pragma unroll
    for (int t = 0; t < 32; t++){
        int j = t*64 + lane;
        float dx = cx - cbp[j*3+0], dy = cy - cbp[j*3+1], dz = cz - cbp[j*3+2];
        d[t] = dx*dx + dy*dy + dz*dz;
    }
    float md = d[0]; int mj = lane;
    #pragma unroll
    for (int t = 1; t < 32; t++){
        int jt = t*64 + lane;
        if (d[t] < md){ md = d[t]; mj = jt; }
    }
    for (int r = 0; r < Kk; r++){
        float bd = md; int bj = mj;
        #pragma unroll
        for (int off = 32; off; off >>= 1){
            float d2 = __shfl_xor(bd, off); int j2 = __shfl_xor(bj, off);
            if (d2 < bd || (d2 == bd && j2 < bj)){ bd = d2; bj = j2; }
        }
        if (lane == 0){
            idx_ws[node*Kk + r] = bj;
            dv_ws[node*Kk + r] = bd;
        }
        if (mj == bj){
            md = 3.4e38f; mj = 0x7fffffff;
            #pragma unroll
            for (int t = 0; t < 32; t++){
                int jt = t*64 + lane;
                if (jt == bj) d[t] = 3.4e38f;
                if (d[t] < md){ md = d[t]; mj = jt; }
            }
        }
    }
}

// ---------------- Kernel F: build all MFMA B-fragments (bf16, fragment-linear) ----------------
// W1F: [nt<34][ks<5][lane][8]  B for edge GEMM1; rows k<128 -> eW1[128+k] (j), k<137 -> eW1[256+k-128] (enc)
// WPF: [nt<34][ks<4][lane][8]  B for pmat GEMM;  rows k<128 -> eW1[k] (i)
// W2F: [s<17][lane][8]         B for GEMM2 (eW2)
__global__ __launch_bounds__(256) void fragw_kernel(const float* __restrict__ eW1,
        const float* __restrict__ eW2,
        unsigned short* __restrict__ W1F, unsigned short* __restrict__ WPF,
        unsigned short* __restrict__ W2F){
    int i0 = blockIdx.x * 256 + threadIdx.x;
    int stride = gridDim.x * 256;
    for (int i = i0; i < 34*5*512; i += stride){
        int j = i & 7, lane = (i >> 3) & 63, t = i >> 9;
        int ks = t % 5, nt = t / 5;
        int cg = nt*16 + (lane & 15);
        int k = ks*32 + ((lane >> 4) << 3) + j;
        float v = 0.f;
        if (cg < H1){
            if (k < 128) v = eW1[(size_t)(128+k)*H1 + cg];
            else if (k < 137) v = eW1[(size_t)(256+(k-128))*H1 + cg];
        }
        W1F[i] = f2bf(v);
    }
    for (int i = i0; i < 34*4*512; i += stride){
        int j = i & 7, lane = (i >> 3) & 63, t = i >> 9;
        int ks = t & 3, nt = t >> 2;
        int cg = nt*16 + (lane & 15);
        int k = ks*32 + ((lane >> 4) << 3) + j;
        float v = (cg < H1) ? eW1[(size_t)k*H1 + cg] : 0.f;
        WPF[i] = f2bf(v);
    }
    for (int i = i0; i < 17*512; i += stride){
        int j = i & 7, lane = (i >> 3) & 63, s = i >> 9;
        int k = s*32 + ((lane >> 4) << 3) + j;
        int col = lane & 15;
        W2F[i] = (k < H1) ? f2bf(eW2[(size_t)k*MD + col]) : (unsigned short)0;
    }
}

// ---------------- Kernel B: P_i = feats @ eW1_i + eb1 via MFMA, zero LDS ---------------------
__global__ __launch_bounds__(256) void pmat_kernel(const float* __restrict__ feats,
        const unsigned short* __restrict__ WPF, const float* __restrict__ eb1,
        float* __restrict__ P){
    int tid = threadIdx.x;
    int wid = tid >> 6, lane = tid & 63;
    int node0 = blockIdx.x * 32;
    int kg = (lane >> 4) * 8;
    s16x8 af[2][4];
    #pragma unroll
    for (int m = 0; m < 2; m++){
        const float* fr = feats + (size_t)(node0 + m*16 + (lane & 15)) * DIMd;
        #pragma unroll
        for (int ks = 0; ks < 4; ks++){
            f32x4 lo = *(const f32x4*)(fr + ks*32 + kg);
            f32x4 hi = *(const f32x4*)(fr + ks*32 + kg + 4);
            union { s16x8 v; unsigned u[4]; } pk;
            pk.u[0] = cvt_pk_bf16(lo[0], lo[1]); pk.u[1] = cvt_pk_bf16(lo[2], lo[3]);
            pk.u[2] = cvt_pk_bf16(hi[0], hi[1]); pk.u[3] = cvt_pk_bf16(hi[2], hi[3]);
            af[m][ks] = pk.v;
        }
    }
    const s16x8* WPFv = (const s16x8*)WPF;
    for (int nt = wid; nt < 34; nt += 4){
        f32x4 acc0 = {0,0,0,0}, acc1 = {0,0,0,0};
        #pragma unroll
        for (int ks = 0; ks < 4; ks++){
            s16x8 bb = WPFv[(nt*4 + ks)*64 + lane];
            acc0 = __builtin_amdgcn_mfma_f32_16x16x32_bf16(af[0][ks], bb, acc0, 0, 0, 0);
            acc1 = __builtin_amdgcn_mfma_f32_16x16x32_bf16(af[1][ks], bb, acc1, 0, 0, 0);
        }
        int cg = nt*16 + (lane & 15);
        if (cg < H1){
            float b = eb1[cg];
            int r0 = (lane >> 4) * 4;
            #pragma unroll
            for (int r = 0; r < 4; r++){
                P[(size_t)(node0 + r0 + r)*PW2 + cg]      = acc0[r] + b;
                P[(size_t)(node0 + 16 + r0 + r)*PW2 + cg] = acc1[r] + b;
            }
        }
    }
}

// ---------------- Kernel C: per-node edge pipeline, GEMM1 via MFMA ---------------------------
__global__ __launch_bounds__(256, 4) void edge_kernel(const float* __restrict__ coors,
        const float* __restrict__ feats, const float* __restrict__ eb2,
        const float* __restrict__ cW1, const float* __restrict__ cb1,
        const float* __restrict__ cW2, const float* __restrict__ cb2,
        const float* __restrict__ P, const unsigned short* __restrict__ W1F,
        const unsigned short* __restrict__ W2F,
        const int* __restrict__ idx_ws, const float* __restrict__ dv_ws,
        float* __restrict__ mi_ws, float* __restrict__ coors_out){
    __shared__ unsigned short Hs[Kk][HSP];           // 35328 B
    __shared__ float Pi_lds[544];                    // 2176 B (530 real, pad 0)
    __shared__ __align__(16) unsigned short aenc[Kk][32];  // 2048 B; overlaid by m_s after GEMM1
    __shared__ int js[Kk];
    __shared__ float rels[Kk][3];
    __shared__ float cacc[4][3];
    float (*m_s)[MD] = (float (*)[MD])aenc;

    int node = blockIdx.x; int tid = threadIdx.x;
    int b = node >> 11;
    int wid = tid >> 6, lane = tid & 63;

    // stage Pi (fp32) and enc/rels/js
    const float* Pn = P + (size_t)node*PW2;
    Pi_lds[tid]       = Pn[tid];
    Pi_lds[tid + 256] = (tid + 256 < PW2) ? Pn[tid + 256] : 0.f;
    if (tid < 32) Pi_lds[512 + tid] = (512 + tid < PW2) ? Pn[512 + tid] : 0.f;
    if (tid < Kk){
        int j = idx_ws[node*Kk + tid];
        float dv = dv_ws[node*Kk + tid];
        js[tid] = j;
        unsigned short e[9];
        e[0] = f2bf(sinf(dv));        e[1] = f2bf(sinf(dv*0.5f));
        e[2] = f2bf(sinf(dv*0.25f));  e[3] = f2bf(sinf(dv*0.125f));
        e[4] = f2bf(cosf(dv));        e[5] = f2bf(cosf(dv*0.5f));
        e[6] = f2bf(cosf(dv*0.25f));  e[7] = f2bf(cosf(dv*0.125f));
        e[8] = f2bf(dv);
        #pragma unroll
        for (int q = 0; q < 9; q++) aenc[tid][q] = e[q];
        #pragma unroll
        for (int q = 9; q < 32; q++) aenc[tid][q] = 0;
        int jg = (b << 11) + j;
        rels[tid][0] = coors[node*3+0] - coors[jg*3+0];
        rels[tid][1] = coors[node*3+1] - coors[jg*3+1];
        rels[tid][2] = coors[node*3+2] - coors[jg*3+2];
    }
    __syncthreads();

    // A-fragments in registers: [feats_j | enc | 0] rows = this wave's 32 neighbors
    int kg = (lane >> 4) * 8;
    s16x8 af[2][5];
    #pragma unroll
    for (int m = 0; m < 2; m++){
        int row = m*16 + (lane & 15);
        int jgl = (b << 11) + js[row];
        const float* fr = feats + (size_t)jgl * DIMd;
        #pragma unroll
        for (int ks = 0; ks < 4; ks++){
            f32x4 lo = *(const f32x4*)(fr + ks*32 + kg);
            f32x4 hi = *(const f32x4*)(fr + ks*32 + kg + 4);
            union { s16x8 v; unsigned u[4]; } pk;
            pk.u[0] = cvt_pk_bf16(lo[0], lo[1]); pk.u[1] = cvt_pk_bf16(lo[2], lo[3]);
            pk.u[2] = cvt_pk_bf16(hi[0], hi[1]); pk.u[3] = cvt_pk_bf16(hi[2], hi[3]);
            af[m][ks] = pk.v;
        }
        af[m][4] = *(const s16x8*)(&aenc[row][kg]);
    }

    // GEMM1: H(32x530) = A(32x160) @ W1F(160x530); epilogue +Pi, silu, ->bf16 Hs
    const s16x8* W1Fv = (const s16x8*)W1F;
    for (int nt = wid; nt < 34; nt += 4){
        f32x4 acc0 = {0,0,0,0}, acc1 = {0,0,0,0};
        #pragma unroll
        for (int ks = 0; ks < 5; ks++){
            s16x8 bb = W1Fv[(nt*5 + ks)*64 + lane];
            acc0 = __builtin_amdgcn_mfma_f32_16x16x32_bf16(af[0][ks], bb, acc0, 0, 0, 0);
            acc1 = __builtin_amdgcn_mfma_f32_16x16x32_bf16(af[1][ks], bb, acc1, 0, 0, 0);
        }
        int cg = nt*16 + (lane & 15);
        bool valid = cg < H1;
        float pic = Pi_lds[cg];
        int r0 = (lane >> 4) * 4;
        #pragma unroll
        for (int r = 0; r < 4; r++){
            float x0 = acc0[r] + pic, x1 = acc1[r] + pic;
            Hs[r0 + r][cg]      = valid ? f2bf(silu_f(x0)) : (unsigned short)0;
            Hs[16 + r0 + r][cg] = valid ? f2bf(silu_f(x1)) : (unsigned short)0;
        }
    }
    __syncthreads();

    // GEMM2: m_raw = H(32x530+pad) @ eW2(530x16)
    if (wid < 2){
        f32x4 acc = {0.f,0.f,0.f,0.f};
        int ar = wid*16 + (lane & 15);
        const s16x8* W2Fv = (const s16x8*)W2F;
        for (int s = 0; s < 17; s++){
            s16x8 a  = *(const s16x8*)(&Hs[ar][s*32 + kg]);
            s16x8 bb = W2Fv[s*64 + lane];
            acc = __builtin_amdgcn_mfma_f32_16x16x32_bf16(a, bb, acc, 0, 0, 0);
        }
        int col = lane & 15, r0 = (lane >> 4) * 4;
        #pragma unroll
        for (int r = 0; r < 4; r++) m_s[wid*16 + r0 + r][col] = acc[r];
    }
    __syncthreads();
    for (int t = tid; t < Kk*MD; t += 256){
        int n = t >> 4, f = t & 15;
        m_s[n][f] = silu_f(m_s[n][f] + eb2[f]);
    }
    __syncthreads();
    if (tid < MD){
        float s = 0.f;
        for (int n = 0; n < Kk; n++) s += m_s[n][tid];
        mi_ws[node*MD + tid] = s;
    }
    // cw MLP (16->64->1) per edge, 8 edges per wave; accumulate cw * rel_coors
    float ax = 0.f, ay = 0.f, az = 0.f;
    for (int q = 0; q < 8; q++){
        int n = wid*8 + q;
        float acc = cb1[lane];
        #pragma unroll
        for (int f = 0; f < MD; f++) acc += m_s[n][f] * cW1[f*64 + lane];
        float p = silu_f(acc) * cW2[lane];
        #pragma unroll
        for (int off = 32; off; off >>= 1) p += __shfl_xor(p, off);
        float cw = p + cb2[0];
        ax += cw * rels[n][0];
        ay += cw * rels[n][1];
        az += cw * rels[n][2];
    }
    if (lane == 0){ cacc[wid][0] = ax; cacc[wid][1] = ay; cacc[wid][2] = az; }
    __syncthreads();
    if (tid == 0){
        coors_out[node*3+0] = cacc[0][0]+cacc[1][0]+cacc[2][0]+cacc[3][0] + coors[node*3+0];
        coors_out[node*3+1] = cacc[0][1]+cacc[1][1]+cacc[2][1]+cacc[3][1] + coors[node*3+1];
        coors_out[node*3+2] = cacc[0][2]+cacc[1][2]+cacc[2][2]+cacc[3][2] + coors[node*3+2];
    }
}

// ---------------- Kernel D: node MLP with residual, packed-f32 -------------------------------
__global__ __launch_bounds__(256) void node_kernel(const float* __restrict__ feats,
        const float* __restrict__ mi_ws,
        const float* __restrict__ nW1, const float* __restrict__ nb1,
        const float* __restrict__ nW2, const float* __restrict__ nb2,
        float* __restrict__ out){
    __shared__ float insT[NDI][12];
    __shared__ float hsdT[NDH][12];
    int tid = threadIdx.x;
    int node0 = blockIdx.x * 8;
    for (int t = tid; t < 8*DIMd; t += 256){
        int m = t >> 7, k = t & 127;
        insT[k][m] = feats[(size_t)node0*DIMd + t];
    }
    if (tid < 8*MD) insT[DIMd + (tid & 15)][tid >> 4] = mi_ws[node0*MD + tid];
    __syncthreads();
    float bias = nb1[tid];
    f32x2 acc[4];
    #pragma unroll
    for (int p = 0; p < 4; p++) acc[p] = (f32x2){bias, bias};
    for (int k = 0; k < NDI; k++){
        float wv = nW1[(size_t)k*NDH + tid];
        f32x2 w2 = {wv, wv};
        acc[0] += *(const f32x2*)&insT[k][0] * w2;
        acc[1] += *(const f32x2*)&insT[k][2] * w2;
        acc[2] += *(const f32x2*)&insT[k][4] * w2;
        acc[3] += *(const f32x2*)&insT[k][6] * w2;
    }
    #pragma unroll
    for (int p = 0; p < 4; p++) *(f32x2*)&hsdT[tid][2*p] = silu2(acc[p]);
    __syncthreads();
    int c = tid & 127, half = tid >> 7;
    float b2 = nb2[c];
    f32x2 a0 = {b2, b2}, a1 = {b2, b2};
    for (int k = 0; k < NDH; k++){
        float wv = nW2[(size_t)k*DIMd + c];
        f32x2 w2 = {wv, wv};
        a0 += *(const f32x2*)&hsdT[k][half*4]     * w2;
        a1 += *(const f32x2*)&hsdT[k][half*4 + 2] * w2;
    }
    #pragma unroll
    for (int q = 0; q < 4; q++){
        int m = half*4 + q;
        float v = (q < 2) ? a0[q & 1] : a1[q & 1];
        out[(size_t)(node0+m)*DIMd + c] = v + feats[(size_t)(node0+m)*DIMd + c];
    }
}

extern "C" void kernel_launch(void* const* d_in, const int* in_sizes, int n_in,
                              void* d_out, int out_size, void* d_ws, size_t ws_size,
                              hipStream_t stream){
    const float* feats = (const float*)d_in[0];
    const float* coors = (const float*)d_in[1];
    const float* eW1 = (const float*)d_in[2];
    const float* eb1 = (const float*)d_in[3];
    const float* eW2 = (const float*)d_in[4];
    const float* eb2 = (const float*)d_in[5];
    const float* cW1 = (const float*)d_in[6];
    const float* cb1 = (const float*)d_in[7];
    const float* cW2 = (const float*)d_in[8];
    const float* cb2 = (const float*)d_in[9];
    const float* nW1 = (const float*)d_in[10];
    const float* nb1 = (const float*)d_in[11];
    const float* nW2 = (const float*)d_in[12];
    const float* nb2 = (const float*)d_in[13];
    float* out = (float*)d_out;                        // node_out: 4*2048*128
    float* coors_out = out + (size_t)Bb*Nn*DIMd;       // coors_out: 4*2048*3

    char* ws = (char*)d_ws;
    int*   idx_ws = (int*)ws;                                     // 1 MB
    float* dv_ws  = (float*)(ws + (1u<<20));                      // 1 MB
    float* Pd     = (float*)(ws + (2u<<20));                      // 8192*530*4 = 17,367,040
    float* mi_ws  = (float*)(ws + (2u<<20) + 17367040u);          // 512 KB
    unsigned short* W1F = (unsigned short*)(ws + (2u<<20) + 17367040u + 524288u);            // 174,080
    unsigned short* WPF = (unsigned short*)(ws + (2u<<20) + 17367040u + 524288u + 174080u);  // 139,264
    unsigned short* W2F = (unsigned short*)(ws + (2u<<20) + 17367040u + 524288u + 174080u + 139264u); // 17,408

    fragw_kernel<<<256, 256, 0, stream>>>(eW1, eW2, W1F, WPF, W2F);
    pmat_kernel<<<Bb*Nn/32, 256, 0, stream>>>(feats, WPF, eb1, Pd);
    topk_kernel<<<Bb*Nn/4, 256, 0, stream>>>(coors, idx_ws, dv_ws);
    edge_kernel<<<Bb*Nn, 256, 0, stream>>>(coors, feats, eb2, cW1, cb1, cW2, cb2,
                                           Pd, W1F, W2F, idx_ws, dv_ws, mi_ws, coors_out);
    node_kernel<<<Bb*Nn/8, 256, 0, stream>>>(feats, mi_ws, nW1, nb1, nW2, nb2, out);
}